// Round 4
// baseline (10627.126 us; speedup 1.0000x reference)
//
#include <hip/hip_runtime.h>
#include <math.h>

#define TT 512
#define BB 64
#define DIN 256
#define HH 512
#define DOUT 256

#define AS 772          // padded k-stride (772 % 32 == 4, mult of 4 for float4)
#define GS 33           // gates LDS stride

#define W_FLOATS (32*AS)
#define A_FLOATS (16*AS)
#define SMEM_FLOATS (W_FLOATS + A_FLOATS + 16*GS + 32 + 128)

#define FCS 516         // fc LDS stride (516 % 32 == 4)

// ---------------- staging helpers ----------------
__device__ __forceinline__ void load_w(float* __restrict__ w_l, float* __restrict__ b_l,
                                       const float* __restrict__ Whh,
                                       const float* __restrict__ Wih,
                                       const float* __restrict__ bias,
                                       int u0, int tid) {
    // 32 gate-cols: cc -> global gate-col C = (cc>>3)*512 + u0 + (cc&7)
    // row layout in LDS: k in [0,512) = Whh, k in [512,768) = Wih
    for (int r = 0; r < 24; ++r) {
        int id = tid + 256*r;           // 0..6143 (32 rows * 192 float4)
        int cc = id / 192;
        int j  = id % 192;
        int C  = (cc >> 3)*HH + u0 + (cc & 7);
        float4 v;
        int k;
        if (j < 128) { v = ((const float4*)(Whh + (size_t)C*HH))[j];       k = 4*j; }
        else         { v = ((const float4*)(Wih + (size_t)C*DIN))[j-128];  k = 512 + 4*(j-128); }
        *(float4*)(w_l + cc*AS + k) = v;
    }
    if (tid < 32) {
        int C = (tid >> 3)*HH + u0 + (tid & 7);
        b_l[tid] = bias[C];
    }
}

__device__ __forceinline__ void stage_x(float* __restrict__ a_l,
                                        const float* __restrict__ src, // row base for b0
                                        int tid) {
    // 16 rows x 64 float4 into a_l[b][512..768)
    for (int r = 0; r < 4; ++r) {
        int id = tid + 256*r;
        int b = id >> 6, j = id & 63;
        float4 v = ((const float4*)(src + (size_t)b*DIN))[j];
        *(float4*)(a_l + b*AS + 512 + 4*j) = v;
    }
}

__device__ __forceinline__ void stage_x_zero(float* __restrict__ a_l, int tid) {
    for (int r = 0; r < 4; ++r) {
        int id = tid + 256*r;
        int b = id >> 6, j = id & 63;
        *(float4*)(a_l + b*AS + 512 + 4*j) = make_float4(0.f,0.f,0.f,0.f);
    }
}

// ---------------- persistent LSTM kernel ----------------
// h exchange: 8B messages {low32 = f32 h bits, high32 = tag = step+1}.
// Single-hop sync: message IS the flag. hbuf2 must be zeroed before launch.
__global__ __launch_bounds__(256, 1)
void lstm_persist(const float* __restrict__ x, const float* __restrict__ target,
                  const float* __restrict__ h0, const float* __restrict__ c0,
                  const float* __restrict__ eWih, const float* __restrict__ eWhh,
                  const float* __restrict__ eb,
                  const float* __restrict__ dWih, const float* __restrict__ dWhh,
                  const float* __restrict__ db,
                  float* __restrict__ hs, unsigned long long* __restrict__ hbuf2)
{
    extern __shared__ float sm[];
    float* w_l = sm;                    // 32 x AS
    float* a_l = sm + W_FLOATS;         // 16 x AS  ([h | x])
    float* g_l = a_l + A_FLOATS;        // 16 x GS
    float* b_l = g_l + 16*GS;           // 32
    float* c_l = b_l + 32;              // 128  (16 b x 8 u)

    const int tid = (int)threadIdx.x;
    // XCD-aware mapping: group ib (16 batches) lives on XCD pair {2ib,2ib+1}.
    const int xcd = (int)(blockIdx.x & 7);
    const int ib  = xcd >> 1;                  // batch group 0..3 (independent)
    const int sub = xcd & 1;
    const int ij  = (int)(blockIdx.x >> 3) | (sub << 5);   // producer id 0..63
    const int b0  = ib * 16;
    const int u0  = ij * 8;

    // encoder weights + bias
    load_w(w_l, b_l, eWhh, eWih, eb, u0, tid);
    if (tid < 128) {
        int b = tid >> 3, u = tid & 7;
        c_l[tid] = c0[(size_t)(b0 + b)*HH + u0 + u];
    }
    stage_x(a_l, x + (size_t)b0*DIN, tid);     // x for s=0
    // h_{-1} = h0 directly into LDS
    for (int r = 0; r < 8; ++r) {
        int id = tid + 256*r;
        int b = id >> 7, j = id & 127;
        float4 v = ((const float4*)(h0 + (size_t)(b0 + b)*HH))[j];
        *(float4*)(a_l + b*AS + 4*j) = v;
    }
    __syncthreads();

    const int kc = tid & 7;            // k-chunk lane (low 3 bits -> shfl_xor 1/2/4)
    const int bt = (tid >> 3) & 3;     // 4 row-groups of 4
    const int ct = tid >> 5;           // 8 col-groups of 4

    for (int s = 0; s < 1024; ++s) {
        // ---- 1. speculatively issue all 32 h-message loads (8B each) ----
        unsigned long long hv[32];
        const unsigned long long* hsrc =
            hbuf2 + (size_t)(s & 1)*BB*HH + (size_t)b0*HH;
        if (s > 0) {
            #pragma unroll
            for (int r = 0; r < 32; ++r)
                hv[r] = __hip_atomic_load(&hsrc[r*256 + tid],
                        __ATOMIC_RELAXED, __HIP_MEMORY_SCOPE_AGENT);
        }

        // ---- 2. phase A: x-part GEMM (k = 512..768), overlaps message flight ----
        float acc[4][4] = {};
        {
            const float* ap = a_l + (bt*4)*AS + 512 + 4*kc;
            const float* wp = w_l + (ct*4)*AS + 512 + 4*kc;
            #pragma unroll
            for (int i = 0; i < 8; ++i) {
                float4 av[4], wv[4];
                #pragma unroll
                for (int q = 0; q < 4; ++q) av[q] = *(const float4*)(ap + q*AS + 32*i);
                #pragma unroll
                for (int q = 0; q < 4; ++q) wv[q] = *(const float4*)(wp + q*AS + 32*i);
                #pragma unroll
                for (int b2 = 0; b2 < 4; ++b2)
                    #pragma unroll
                    for (int c2 = 0; c2 < 4; ++c2)
                        acc[b2][c2] += av[b2].x*wv[c2].x + av[b2].y*wv[c2].y
                                     + av[b2].z*wv[c2].z + av[b2].w*wv[c2].w;
            }
        }

        // ---- 3. tag-check + retry stale messages; spill to LDS ----
        if (s > 0) {
            unsigned pend = 0xFFFFFFFFu;
            while (true) {
                unsigned np = 0;
                #pragma unroll
                for (int r = 0; r < 32; ++r)
                    if ((pend & (1u << r)) && ((unsigned)(hv[r] >> 32) < (unsigned)s))
                        np |= (1u << r);
                pend = np;
                if (!pend) break;
                #pragma unroll
                for (int r = 0; r < 32; ++r)
                    if (pend & (1u << r))
                        hv[r] = __hip_atomic_load(&hsrc[r*256 + tid],
                                __ATOMIC_RELAXED, __HIP_MEMORY_SCOPE_AGENT);
            }
            // spill: element e = r*256+tid -> b = r>>1, u = (r&1)*256+tid
            #pragma unroll
            for (int r = 0; r < 32; ++r)
                a_l[(r >> 1)*AS + (r & 1)*256 + tid] =
                    __uint_as_float((unsigned)(hv[r] & 0xFFFFFFFFu));
            __syncthreads();
        }

        // ---- 4. phase B: h-part GEMM (k = 0..512) ----
        {
            const float* ap = a_l + (bt*4)*AS + 4*kc;
            const float* wp = w_l + (ct*4)*AS + 4*kc;
            #pragma unroll 4
            for (int i = 0; i < 16; ++i) {
                float4 av[4], wv[4];
                #pragma unroll
                for (int q = 0; q < 4; ++q) av[q] = *(const float4*)(ap + q*AS + 32*i);
                #pragma unroll
                for (int q = 0; q < 4; ++q) wv[q] = *(const float4*)(wp + q*AS + 32*i);
                #pragma unroll
                for (int b2 = 0; b2 < 4; ++b2)
                    #pragma unroll
                    for (int c2 = 0; c2 < 4; ++c2)
                        acc[b2][c2] += av[b2].x*wv[c2].x + av[b2].y*wv[c2].y
                                     + av[b2].z*wv[c2].z + av[b2].w*wv[c2].w;
            }
        }
        // reduce over the 8 k-chunk lanes
        #pragma unroll
        for (int b2 = 0; b2 < 4; ++b2)
            #pragma unroll
            for (int c2 = 0; c2 < 4; ++c2) {
                float v = acc[b2][c2];
                v += __shfl_xor(v, 1, 64);
                v += __shfl_xor(v, 2, 64);
                v += __shfl_xor(v, 4, 64);
                acc[b2][c2] = v;
            }
        if (kc == 0) {
            #pragma unroll
            for (int b2 = 0; b2 < 4; ++b2)
                #pragma unroll
                for (int c2 = 0; c2 < 4; ++c2)
                    g_l[(bt*4 + b2)*GS + ct*4 + c2] = acc[b2][c2] + b_l[ct*4 + c2];
        }
        __syncthreads();

        // ---- 5. elementwise update; publish fused {h|tag} message ----
        float hval = 0.f;
        if (tid < 128) {
            int b = tid >> 3, u = tid & 7;
            float gi = g_l[b*GS + u];
            float gf = g_l[b*GS + 8 + u];
            float gg = g_l[b*GS + 16 + u];
            float go = g_l[b*GS + 24 + u];
            float ii = 1.f / (1.f + expf(-gi));
            float ff = 1.f / (1.f + expf(-gf));
            float g2 = tanhf(gg);
            float oo = 1.f / (1.f + expf(-go));
            float c  = ff * c_l[tid] + ii * g2;
            c_l[tid] = c;
            hval = oo * tanhf(c);
            int gb = b0 + b, gu = u0 + u;
            unsigned long long msg = ((unsigned long long)(unsigned)(s + 1) << 32)
                                   | (unsigned long long)__float_as_uint(hval);
            __hip_atomic_store(&hbuf2[(size_t)((s & 1) ^ 1)*BB*HH + (size_t)gb*HH + gu],
                               msg, __ATOMIC_RELAXED, __HIP_MEMORY_SCOPE_AGENT);
        }

        // ---- 6. off-critical-path tail: hs output, next x, decoder W swap ----
        if (s >= 512 && tid < 128) {
            int b = tid >> 3, u = tid & 7;
            hs[((size_t)(s - 512)*BB + (b0 + b))*HH + (u0 + u)] = hval;
        }
        if (s == 511) {
            __syncthreads();            // everyone done with encoder W reads
            load_w(w_l, b_l, dWhh, dWih, db, u0, tid);
        }
        int ns = s + 1;
        if (ns < 1024) {
            if (ns == 512)       stage_x_zero(a_l, tid);
            else if (ns < 512)   stage_x(a_l, x + ((size_t)ns*BB + b0)*DIN, tid);
            else                 stage_x(a_l, target + ((size_t)(ns - 513)*BB + b0)*DOUT, tid);
        }
        __syncthreads();   // staged x + (new W) + g_l reuse ordering
    }
}

// ---------------- FC (logits) kernel ----------------
__global__ __launch_bounds__(256, 1)
void fc_kernel(const float* __restrict__ hs, const float* __restrict__ W,
               const float* __restrict__ bias, float* __restrict__ out)
{
    extern __shared__ float sm[];
    float* hs_l = sm;              // 16 x FCS
    float* w_l  = sm + 16*FCS;     // 32 x FCS

    const int tid = (int)threadIdx.x;
    const int rb = (int)(blockIdx.x >> 3);    // 2048 row-blocks of 16
    const int cb = (int)(blockIdx.x & 7);     // 8 col-blocks of 32

    for (int r = 0; r < 8; ++r) {
        int id = tid + 256*r;
        int b = id >> 7, j = id & 127;
        float4 v = ((const float4*)(hs + (size_t)(rb*16 + b)*HH))[j];
        *(float4*)(hs_l + b*FCS + 4*j) = v;
    }
    for (int r = 0; r < 16; ++r) {
        int id = tid + 256*r;
        int c = id >> 7, j = id & 127;
        float4 v = ((const float4*)(W + (size_t)(cb*32 + c)*HH))[j];
        *(float4*)(w_l + c*FCS + 4*j) = v;
    }
    __syncthreads();

    const int kc = tid & 7, bt = (tid >> 3) & 3, ct = tid >> 5;
    float acc[4][4] = {};
    const float* ap = hs_l + (bt*4)*FCS + 4*kc;
    const float* wp = w_l  + (ct*4)*FCS + 4*kc;
    #pragma unroll 4
    for (int i = 0; i < 16; ++i) {
        float4 av[4], wv[4];
        #pragma unroll
        for (int q = 0; q < 4; ++q) av[q] = *(const float4*)(ap + q*FCS + 32*i);
        #pragma unroll
        for (int q = 0; q < 4; ++q) wv[q] = *(const float4*)(wp + q*FCS + 32*i);
        #pragma unroll
        for (int b2 = 0; b2 < 4; ++b2)
            #pragma unroll
            for (int c2 = 0; c2 < 4; ++c2)
                acc[b2][c2] += av[b2].x*wv[c2].x + av[b2].y*wv[c2].y
                             + av[b2].z*wv[c2].z + av[b2].w*wv[c2].w;
    }
    #pragma unroll
    for (int b2 = 0; b2 < 4; ++b2)
        #pragma unroll
        for (int c2 = 0; c2 < 4; ++c2) {
            float v = acc[b2][c2];
            v += __shfl_xor(v, 1, 64);
            v += __shfl_xor(v, 2, 64);
            v += __shfl_xor(v, 4, 64);
            acc[b2][c2] = v;
        }
    if (kc == 0) {
        #pragma unroll
        for (int b2 = 0; b2 < 4; ++b2)
            #pragma unroll
            for (int c2 = 0; c2 < 4; ++c2) {
                int row = rb*16 + bt*4 + b2;
                int col = cb*32 + ct*4 + c2;
                out[(size_t)row*DOUT + col] = acc[b2][c2] + bias[col];
            }
    }
}

// ---------------- in-place softmax over last dim (256) ----------------
__global__ __launch_bounds__(256, 1)
void softmax_kernel(float* __restrict__ out)
{
    int row  = (int)blockIdx.x * 4 + ((int)threadIdx.x >> 6);
    int lane = (int)threadIdx.x & 63;
    float4 v = ((const float4*)(out + (size_t)row*DOUT))[lane];
    float m = fmaxf(fmaxf(v.x, v.y), fmaxf(v.z, v.w));
    #pragma unroll
    for (int d = 1; d < 64; d <<= 1) m = fmaxf(m, __shfl_xor(m, d, 64));
    float ex = expf(v.x - m), ey = expf(v.y - m), ez = expf(v.z - m), ew = expf(v.w - m);
    float ssum = ex + ey + ez + ew;
    #pragma unroll
    for (int d = 1; d < 64; d <<= 1) ssum += __shfl_xor(ssum, d, 64);
    float inv = 1.f / ssum;
    float4 o = make_float4(ex*inv, ey*inv, ez*inv, ew*inv);
    ((float4*)(out + (size_t)row*DOUT))[lane] = o;
}

// ---------------- launch ----------------
extern "C" void kernel_launch(void* const* d_in, const int* in_sizes, int n_in,
                              void* d_out, int out_size, void* d_ws, size_t ws_size,
                              hipStream_t stream) {
    (void)in_sizes; (void)n_in; (void)out_size; (void)ws_size;
    const float* x      = (const float*)d_in[0];
    const float* target = (const float*)d_in[1];
    const float* h0     = (const float*)d_in[2];
    const float* c0     = (const float*)d_in[3];
    const float* eWih   = (const float*)d_in[4];
    const float* eWhh   = (const float*)d_in[5];
    const float* eb     = (const float*)d_in[6];
    const float* dWih   = (const float*)d_in[7];
    const float* dWhh   = (const float*)d_in[8];
    const float* db     = (const float*)d_in[9];
    const float* fcW    = (const float*)d_in[10];
    const float* fcb    = (const float*)d_in[11];
    float* out = (float*)d_out;

    float* hs = (float*)d_ws;                              // [T*B*H] decoder hidden
    unsigned long long* hbuf2 =
        (unsigned long long*)(hs + (size_t)TT*BB*HH);      // 2*B*H messages (8B)

    // zero message tags (ws is poisoned 0xAA before every call)
    hipMemsetAsync(hbuf2, 0, (size_t)2*BB*HH*sizeof(unsigned long long), stream);

    size_t lds_main = (size_t)SMEM_FLOATS * sizeof(float); // ~151 KB
    lstm_persist<<<dim3(256), dim3(256), lds_main, stream>>>(
        x, target, h0, c0, eWih, eWhh, eb, dWih, dWhh, db, hs, hbuf2);

    size_t lds_fc = (size_t)(48*FCS) * sizeof(float);      // ~99 KB
    fc_kernel<<<dim3(16384), dim3(256), lds_fc, stream>>>(hs, fcW, fcb, out);

    softmax_kernel<<<dim3(8192), dim3(256), 0, stream>>>(out);
}

// Round 5
// 7425.410 us; speedup vs baseline: 1.4312x; 1.4312x over previous
//
#include <hip/hip_runtime.h>
#include <math.h>

#define TT 512
#define BB 64
#define DIN 256
#define HH 512
#define DOUT 256

// f16 row stride: 776 f16 = 388 u32 = 1552 B (16B-aligned rows, conflict-free frags)
#define RSU 388          // row stride in u32
#define RSH 776          // row stride in f16

// LDS layout (u32 units)
#define W_HI_OFF 0
#define W_LO_OFF 12416   // 32*388
#define A_HI_OFF 24832
#define A_LO_OFF 31040   // +16*388
#define P_OFF    37248   // 4 tiles * 320 floats
#define B_OFF    38528   // 32 biases
#define C_OFF    38560   // 128 cell states
#define SMEM_U32 38688
#define SMEM_BYTES (SMEM_U32*4)

#define FCS 516          // fc LDS stride

typedef _Float16 f16x8 __attribute__((ext_vector_type(8)));
typedef float    f32x4 __attribute__((ext_vector_type(4)));

union H16 { _Float16 f; unsigned short u; };

__device__ __forceinline__ unsigned short f16bits(_Float16 h) { H16 t; t.f = h; return t.u; }

// split x,y into f16 hi + scaled-lo (lo = (x-hi)*2048 stays in f16 normal range)
__device__ __forceinline__ void pack2(float x, float y, unsigned& hi, unsigned& lo) {
    _Float16 hx = (_Float16)x, hy = (_Float16)y;
    _Float16 lx = (_Float16)((x - (float)hx) * 2048.0f);
    _Float16 ly = (_Float16)((y - (float)hy) * 2048.0f);
    hi = (unsigned)f16bits(hx) | ((unsigned)f16bits(hy) << 16);
    lo = (unsigned)f16bits(lx) | ((unsigned)f16bits(ly) << 16);
}

// ---------------- W staging: fp32 global -> f16 hi/lo in LDS ----------------
__device__ __forceinline__ void load_w_f16(unsigned* __restrict__ sm32, float* __restrict__ b_l,
                                           const float* __restrict__ Whh,
                                           const float* __restrict__ Wih,
                                           const float* __restrict__ bias,
                                           int u0, int tid) {
    // 32 gate-cols x 384 u32 (768 f16) per row; k<512 = Whh, k>=512 = Wih
    for (int r = 0; r < 48; ++r) {
        int id = tid + 256*r;            // 0..12287
        int cc = id / 384;
        int jj = id - cc*384;            // u32 index in row -> k = 2*jj
        int C  = (cc >> 3)*HH + u0 + (cc & 7);
        float2 v;
        if (jj < 256) v = ((const float2*)(Whh + (size_t)C*HH))[jj];
        else          v = ((const float2*)(Wih + (size_t)C*DIN))[jj - 256];
        unsigned hi, lo;
        pack2(v.x, v.y, hi, lo);
        sm32[W_HI_OFF + cc*RSU + jj] = hi;
        sm32[W_LO_OFF + cc*RSU + jj] = lo;
    }
    if (tid < 32) {
        int C = (tid >> 3)*HH + u0 + (tid & 7);
        b_l[tid] = bias[C];
    }
}

// ---------------- x staging: fp32 global -> f16 hi/lo at k in [512,768) ----------------
__device__ __forceinline__ void stage_x_f16(unsigned* __restrict__ sm32,
                                            const float* __restrict__ src, int tid) {
    for (int r = 0; r < 4; ++r) {
        int idx4 = tid + 256*r;          // 1024 float4 = 16 rows x 64
        int b = idx4 >> 6, j4 = idx4 & 63;
        float4 v = ((const float4*)(src + (size_t)b*DIN))[j4];
        unsigned h0, l0, h1, l1;
        pack2(v.x, v.y, h0, l0);
        pack2(v.z, v.w, h1, l1);
        int o = b*RSU + 256 + 2*j4;
        sm32[A_HI_OFF + o]     = h0;
        sm32[A_HI_OFF + o + 1] = h1;
        sm32[A_LO_OFF + o]     = l0;
        sm32[A_LO_OFF + o + 1] = l1;
    }
}

__device__ __forceinline__ void stage_x_zero_f16(unsigned* __restrict__ sm32, int tid) {
    for (int r = 0; r < 4; ++r) {
        int idx4 = tid + 256*r;
        int b = idx4 >> 6, j4 = idx4 & 63;
        int o = b*RSU + 256 + 2*j4;
        sm32[A_HI_OFF + o]     = 0u;
        sm32[A_HI_OFF + o + 1] = 0u;
        sm32[A_LO_OFF + o]     = 0u;
        sm32[A_LO_OFF + o + 1] = 0u;
    }
}

// ---------------- persistent LSTM kernel (split-f16 MFMA) ----------------
// h exchange: packed u32 {f16 hi | f16 lo<<16}; R3 flag+ballot protocol.
__global__ __launch_bounds__(256, 1)
void lstm_persist(const float* __restrict__ x, const float* __restrict__ target,
                  const float* __restrict__ h0, const float* __restrict__ c0,
                  const float* __restrict__ eWih, const float* __restrict__ eWhh,
                  const float* __restrict__ eb,
                  const float* __restrict__ dWih, const float* __restrict__ dWhh,
                  const float* __restrict__ db,
                  float* __restrict__ hs, unsigned* __restrict__ hbuf,
                  unsigned* __restrict__ bar)
{
    extern __shared__ unsigned sm32[];
    float* p_l = (float*)(sm32 + P_OFF);
    float* b_l = (float*)(sm32 + B_OFF);
    float* c_l = (float*)(sm32 + C_OFF);

    const int tid = (int)threadIdx.x;
    const int xcd = (int)(blockIdx.x & 7);
    const int ib  = xcd >> 1;                  // batch group 0..3 (independent)
    const int sub = xcd & 1;
    const int ij  = (int)(blockIdx.x >> 3) | (sub << 5);   // producer id 0..63
    const int b0  = ib * 16;
    const int u0  = ij * 8;
    unsigned* gflags = bar + ib*64;            // 64 monotonic per-producer flags

    load_w_f16(sm32, b_l, eWhh, eWih, eb, u0, tid);
    if (tid < 128) {
        int b = tid >> 3, u = tid & 7;
        c_l[tid] = c0[(size_t)(b0 + b)*HH + u0 + u];
    }
    stage_x_f16(sm32, x + (size_t)b0*DIN, tid);     // x for s=0
    __syncthreads();

    const int lane = tid & 63;
    const int wid  = tid >> 6;
    const int m    = lane & 15;        // A row (batch) / B col (gate-col)
    const int q    = lane >> 4;        // quad -> k-subchunk
    const int ct   = wid & 1;          // col-tile (16 cols)
    const int kh   = wid >> 1;         // k-half (12 of 24 k-steps)

    const _Float16* aH = (const _Float16*)(sm32 + A_HI_OFF);
    const _Float16* aL = (const _Float16*)(sm32 + A_LO_OFF);
    const _Float16* wH = (const _Float16*)(sm32 + W_HI_OFF);
    const _Float16* wL = (const _Float16*)(sm32 + W_LO_OFF);
    const int aoff = m*RSH + q*8;
    const int woff = (ct*16 + m)*RSH + q*8;

    for (int s = 0; s < 1024; ++s) {
        // ---- 1. wait for producers of step s-1; gather+unpack h ----
        if (s > 0) {
            if (tid < 64) {
                while (true) {
                    unsigned v = __hip_atomic_load(&gflags[tid], __ATOMIC_RELAXED,
                                                   __HIP_MEMORY_SCOPE_AGENT);
                    if (__ballot(v >= (unsigned)s) == ~0ull) break;
                    __builtin_amdgcn_s_sleep(1);
                }
            }
            __syncthreads();
            const unsigned long long* hsrc = (const unsigned long long*)
                (hbuf + (size_t)(s & 1)*BB*HH + (size_t)b0*HH);
            #pragma unroll
            for (int r = 0; r < 16; ++r) {
                int idx2 = tid + 256*r;          // 4096 uint2 = 16 rows x 256
                unsigned long long v = __hip_atomic_load(&hsrc[idx2],
                        __ATOMIC_RELAXED, __HIP_MEMORY_SCOPE_AGENT);
                int b = idx2 >> 8, jp = idx2 & 255;
                unsigned lo32 = (unsigned)v, hi32 = (unsigned)(v >> 32);
                int o = b*RSU + jp;
                sm32[A_HI_OFF + o] = (lo32 & 0xFFFFu) | (hi32 << 16);
                sm32[A_LO_OFF + o] = (lo32 >> 16)     | (hi32 & 0xFFFF0000u);
            }
        } else {
            // h_{-1} = h0 (fp32) -> split
            for (int r = 0; r < 8; ++r) {
                int idx4 = tid + 256*r;          // 2048 float4 = 16 rows x 128
                int b = idx4 >> 7, j4 = idx4 & 127;
                float4 v = ((const float4*)(h0 + (size_t)(b0 + b)*HH))[j4];
                unsigned h0p, l0p, h1p, l1p;
                pack2(v.x, v.y, h0p, l0p);
                pack2(v.z, v.w, h1p, l1p);
                int o = b*RSU + 2*j4;
                sm32[A_HI_OFF + o]     = h0p;
                sm32[A_HI_OFF + o + 1] = h1p;
                sm32[A_LO_OFF + o]     = l0p;
                sm32[A_LO_OFF + o + 1] = l1p;
            }
        }
        __syncthreads();

        // ---- 2. split-f16 MFMA GEMM: gates[16b x 32c] over k=768 ----
        f32x4 Chh = {0.f, 0.f, 0.f, 0.f};
        f32x4 Chl = {0.f, 0.f, 0.f, 0.f};
        f32x4 Clh = {0.f, 0.f, 0.f, 0.f};
        {
            const int ks0 = kh * 12;
            #pragma unroll
            for (int i = 0; i < 12; ++i) {
                const int o = (ks0 + i) * 32;
                f16x8 ah = *(const f16x8*)(aH + aoff + o);
                f16x8 al = *(const f16x8*)(aL + aoff + o);
                f16x8 wh = *(const f16x8*)(wH + woff + o);
                f16x8 wl = *(const f16x8*)(wL + woff + o);
                Chh = __builtin_amdgcn_mfma_f32_16x16x32_f16(ah, wh, Chh, 0, 0, 0);
                Chl = __builtin_amdgcn_mfma_f32_16x16x32_f16(ah, wl, Chl, 0, 0, 0);
                Clh = __builtin_amdgcn_mfma_f32_16x16x32_f16(al, wh, Clh, 0, 0, 0);
            }
        }
        {
            float4 C;
            const float sc = 1.0f / 2048.0f;
            C.x = Chh[0] + (Chl[0] + Clh[0]) * sc;
            C.y = Chh[1] + (Chl[1] + Clh[1]) * sc;
            C.z = Chh[2] + (Chl[2] + Clh[2]) * sc;
            C.w = Chh[3] + (Chl[3] + Clh[3]) * sc;
            // C/D layout: col = lane&15 (= m), row b = q*4+reg
            *(float4*)(p_l + (ct*2 + kh)*320 + m*20 + q*4) = C;
        }
        __syncthreads();

        // ---- 3. elementwise LSTM update; publish packed {hi|lo} h ----
        float hval = 0.f;
        if (tid < 128) {
            int b = tid >> 3, u = tid & 7;
            float gi = p_l[      u*20 + b] + p_l[320 +      u*20 + b] + b_l[u];
            float gf = p_l[(8+u)*20 + b] + p_l[320 + (8+u)*20 + b] + b_l[8 + u];
            float gg = p_l[640 +   u*20 + b] + p_l[960 +      u*20 + b] + b_l[16 + u];
            float go = p_l[640 + (8+u)*20 + b] + p_l[960 + (8+u)*20 + b] + b_l[24 + u];
            float ii = 1.f / (1.f + expf(-gi));
            float ff = 1.f / (1.f + expf(-gf));
            float g2 = tanhf(gg);
            float oo = 1.f / (1.f + expf(-go));
            float c  = ff * c_l[tid] + ii * g2;
            c_l[tid] = c;
            hval = oo * tanhf(c);
            int gb = b0 + b, gu = u0 + u;
            _Float16 hh = (_Float16)hval;
            _Float16 hl = (_Float16)((hval - (float)hh) * 2048.0f);
            unsigned msg = (unsigned)f16bits(hh) | ((unsigned)f16bits(hl) << 16);
            __hip_atomic_store(&hbuf[(size_t)((s & 1) ^ 1)*BB*HH + (size_t)gb*HH + gu],
                               msg, __ATOMIC_RELAXED, __HIP_MEMORY_SCOPE_AGENT);
        }
        __syncthreads();   // drains vmcnt(0): h stores globally visible

        // ---- 4. publish flag (plain monotonic store, no RMW) ----
        if (tid == 0)
            __hip_atomic_store(&gflags[ij], (unsigned)(s + 1),
                               __ATOMIC_RELAXED, __HIP_MEMORY_SCOPE_AGENT);

        // ---- 5. off-critical-path tail ----
        if (s >= 512 && tid < 128) {
            int b = tid >> 3, u = tid & 7;
            hs[((size_t)(s - 512)*BB + (b0 + b))*HH + (u0 + u)] = hval;
        }
        if (s == 511) load_w_f16(sm32, b_l, dWhh, dWih, db, u0, tid);
        int ns = s + 1;
        if (ns < 1024) {
            if (ns == 512)       stage_x_zero_f16(sm32, tid);
            else if (ns < 512)   stage_x_f16(sm32, x + ((size_t)ns*BB + b0)*DIN, tid);
            else                 stage_x_f16(sm32, target + ((size_t)(ns - 513)*BB + b0)*DOUT, tid);
        }
        __syncthreads();   // staged x / new W visible before next step's MFMA
    }
}

// ---------------- FC (logits) kernel ----------------
__global__ __launch_bounds__(256, 1)
void fc_kernel(const float* __restrict__ hs, const float* __restrict__ W,
               const float* __restrict__ bias, float* __restrict__ out)
{
    extern __shared__ float sm[];
    float* hs_l = sm;              // 16 x FCS
    float* w_l  = sm + 16*FCS;     // 32 x FCS

    const int tid = (int)threadIdx.x;
    const int rb = (int)(blockIdx.x >> 3);
    const int cb = (int)(blockIdx.x & 7);

    for (int r = 0; r < 8; ++r) {
        int id = tid + 256*r;
        int b = id >> 7, j = id & 127;
        float4 v = ((const float4*)(hs + (size_t)(rb*16 + b)*HH))[j];
        *(float4*)(hs_l + b*FCS + 4*j) = v;
    }
    for (int r = 0; r < 16; ++r) {
        int id = tid + 256*r;
        int c = id >> 7, j = id & 127;
        float4 v = ((const float4*)(W + (size_t)(cb*32 + c)*HH))[j];
        *(float4*)(w_l + c*FCS + 4*j) = v;
    }
    __syncthreads();

    const int kc = tid & 7, bt = (tid >> 3) & 3, ct = tid >> 5;
    float acc[4][4] = {};
    const float* ap = hs_l + (bt*4)*FCS + 4*kc;
    const float* wp = w_l  + (ct*4)*FCS + 4*kc;
    #pragma unroll 4
    for (int i = 0; i < 16; ++i) {
        float4 av[4], wv[4];
        #pragma unroll
        for (int q = 0; q < 4; ++q) av[q] = *(const float4*)(ap + q*FCS + 32*i);
        #pragma unroll
        for (int q = 0; q < 4; ++q) wv[q] = *(const float4*)(wp + q*FCS + 32*i);
        #pragma unroll
        for (int b2 = 0; b2 < 4; ++b2)
            #pragma unroll
            for (int c2 = 0; c2 < 4; ++c2)
                acc[b2][c2] += av[b2].x*wv[c2].x + av[b2].y*wv[c2].y
                             + av[b2].z*wv[c2].z + av[b2].w*wv[c2].w;
    }
    #pragma unroll
    for (int b2 = 0; b2 < 4; ++b2)
        #pragma unroll
        for (int c2 = 0; c2 < 4; ++c2) {
            float v = acc[b2][c2];
            v += __shfl_xor(v, 1, 64);
            v += __shfl_xor(v, 2, 64);
            v += __shfl_xor(v, 4, 64);
            acc[b2][c2] = v;
        }
    if (kc == 0) {
        #pragma unroll
        for (int b2 = 0; b2 < 4; ++b2)
            #pragma unroll
            for (int c2 = 0; c2 < 4; ++c2) {
                int row = rb*16 + bt*4 + b2;
                int col = cb*32 + ct*4 + c2;
                out[(size_t)row*DOUT + col] = acc[b2][c2] + bias[col];
            }
    }
}

// ---------------- in-place softmax over last dim (256) ----------------
__global__ __launch_bounds__(256, 1)
void softmax_kernel(float* __restrict__ out)
{
    int row  = (int)blockIdx.x * 4 + ((int)threadIdx.x >> 6);
    int lane = (int)threadIdx.x & 63;
    float4 v = ((const float4*)(out + (size_t)row*DOUT))[lane];
    float m = fmaxf(fmaxf(v.x, v.y), fmaxf(v.z, v.w));
    #pragma unroll
    for (int d = 1; d < 64; d <<= 1) m = fmaxf(m, __shfl_xor(m, d, 64));
    float ex = expf(v.x - m), ey = expf(v.y - m), ez = expf(v.z - m), ew = expf(v.w - m);
    float ssum = ex + ey + ez + ew;
    #pragma unroll
    for (int d = 1; d < 64; d <<= 1) ssum += __shfl_xor(ssum, d, 64);
    float inv = 1.f / ssum;
    float4 o = make_float4(ex*inv, ey*inv, ez*inv, ew*inv);
    ((float4*)(out + (size_t)row*DOUT))[lane] = o;
}

// ---------------- flag init (ws is poisoned 0xAA before every call) ----------------
__global__ void init_kernel(unsigned* __restrict__ bar)
{
    bar[threadIdx.x] = 0u;
}

// ---------------- launch ----------------
extern "C" void kernel_launch(void* const* d_in, const int* in_sizes, int n_in,
                              void* d_out, int out_size, void* d_ws, size_t ws_size,
                              hipStream_t stream) {
    (void)in_sizes; (void)n_in; (void)out_size; (void)ws_size;
    const float* x      = (const float*)d_in[0];
    const float* target = (const float*)d_in[1];
    const float* h0     = (const float*)d_in[2];
    const float* c0     = (const float*)d_in[3];
    const float* eWih   = (const float*)d_in[4];
    const float* eWhh   = (const float*)d_in[5];
    const float* eb     = (const float*)d_in[6];
    const float* dWih   = (const float*)d_in[7];
    const float* dWhh   = (const float*)d_in[8];
    const float* db     = (const float*)d_in[9];
    const float* fcW    = (const float*)d_in[10];
    const float* fcb    = (const float*)d_in[11];
    float* out = (float*)d_out;

    unsigned* bar = (unsigned*)d_ws;                       // 1024 u32 flags
    float* hs = (float*)d_ws + 1024;                       // [T*B*H] decoder hidden
    unsigned* hbuf = (unsigned*)(hs + (size_t)TT*BB*HH);   // 2*B*H packed-f16 h

    init_kernel<<<dim3(1), dim3(1024), 0, stream>>>(bar);

    lstm_persist<<<dim3(256), dim3(256), SMEM_BYTES, stream>>>(
        x, target, h0, c0, eWih, eWhh, eb, dWih, dWhh, db, hs, hbuf, bar);

    size_t lds_fc = (size_t)(48*FCS) * sizeof(float);      // ~99 KB
    fc_kernel<<<dim3(16384), dim3(256), lds_fc, stream>>>(hs, fcW, fcb, out);

    softmax_kernel<<<dim3(8192), dim3(256), 0, stream>>>(out);
}

// Round 6
// 4658.454 us; speedup vs baseline: 2.2813x; 1.5940x over previous
//
#include <hip/hip_runtime.h>
#include <math.h>

#define TT 512
#define BB 64
#define DIN 256
#define HH 512
#define DOUT 256

// f16 row stride: 776 f16 = 388 u32 (16B-aligned rows, conflict-free frags)
#define RSU 388          // row stride in u32
#define RSH 776          // row stride in f16

// LDS layout (u32 units)
#define W_HI_OFF 0
#define W_LO_OFF 12416   // 32*388
#define A_HI_OFF 24832
#define A_LO_OFF 31040   // +16*388
#define P_OFF    37248   // 4 tiles * 320 floats
#define B_OFF    38528   // 32 biases
#define C_OFF    38560   // 128 cell states
#define HST_HI   38688   // 64 u32 (128 u16) h-hi stage
#define HST_LO   38752   // 64 u32 h-lo stage
#define SMEM_U32 38816
#define SMEM_BYTES (SMEM_U32*4)

#define FCS 516          // fc LDS stride

typedef _Float16 f16x8 __attribute__((ext_vector_type(8)));
typedef float    f32x4 __attribute__((ext_vector_type(4)));
typedef unsigned u32x4 __attribute__((ext_vector_type(4)));

union H16 { _Float16 f; unsigned short u; };
__device__ __forceinline__ unsigned short f16bits(_Float16 h) { H16 t; t.f = h; return t.u; }

// split x,y into f16 hi + scaled-lo (lo = (x-hi)*2048 stays in f16 normal range)
__device__ __forceinline__ void pack2(float x, float y, unsigned& hi, unsigned& lo) {
    _Float16 hx = (_Float16)x, hy = (_Float16)y;
    _Float16 lx = (_Float16)((x - (float)hx) * 2048.0f);
    _Float16 ly = (_Float16)((y - (float)hy) * 2048.0f);
    hi = (unsigned)f16bits(hx) | ((unsigned)f16bits(hy) << 16);
    lo = (unsigned)f16bits(lx) | ((unsigned)f16bits(ly) << 16);
}

// coherent (cache-bypass) 16B load/store — reach the coherence point like
// agent-scope atomics, but coalesce as vector memory ops.
__device__ __forceinline__ u32x4 ld16_cohere(const void* p) {
    u32x4 v;
    asm volatile("global_load_dwordx4 %0, %1, off sc0 sc1"
                 : "=&v"(v) : "v"(p) : "memory");
    return v;
}
__device__ __forceinline__ void st16_cohere(void* p, u32x4 v) {
    asm volatile("global_store_dwordx4 %0, %1, off sc0 sc1"
                 :: "v"(p), "v"(v) : "memory");
}

// ---------------- W staging: fp32 global -> f16 hi/lo in LDS ----------------
__device__ __forceinline__ void load_w_f16(unsigned* __restrict__ sm32, float* __restrict__ b_l,
                                           const float* __restrict__ Whh,
                                           const float* __restrict__ Wih,
                                           const float* __restrict__ bias,
                                           int u0, int tid) {
    for (int r = 0; r < 48; ++r) {
        int id = tid + 256*r;            // 0..12287
        int cc = id / 384;
        int jj = id - cc*384;            // u32 index in row -> k = 2*jj
        int C  = (cc >> 3)*HH + u0 + (cc & 7);
        float2 v;
        if (jj < 256) v = ((const float2*)(Whh + (size_t)C*HH))[jj];
        else          v = ((const float2*)(Wih + (size_t)C*DIN))[jj - 256];
        unsigned hi, lo;
        pack2(v.x, v.y, hi, lo);
        sm32[W_HI_OFF + cc*RSU + jj] = hi;
        sm32[W_LO_OFF + cc*RSU + jj] = lo;
    }
    if (tid < 32) {
        int C = (tid >> 3)*HH + u0 + (tid & 7);
        b_l[tid] = bias[C];
    }
}

// ---------------- x staging: fp32 global -> f16 hi/lo at k in [512,768) ----------------
__device__ __forceinline__ void stage_x_f16(unsigned* __restrict__ sm32,
                                            const float* __restrict__ src, int tid) {
    for (int r = 0; r < 4; ++r) {
        int idx4 = tid + 256*r;          // 1024 float4 = 16 rows x 64
        int b = idx4 >> 6, j4 = idx4 & 63;
        float4 v = ((const float4*)(src + (size_t)b*DIN))[j4];
        unsigned h0, l0, h1, l1;
        pack2(v.x, v.y, h0, l0);
        pack2(v.z, v.w, h1, l1);
        int o = b*RSU + 256 + 2*j4;
        sm32[A_HI_OFF + o]     = h0;
        sm32[A_HI_OFF + o + 1] = h1;
        sm32[A_LO_OFF + o]     = l0;
        sm32[A_LO_OFF + o + 1] = l1;
    }
}

__device__ __forceinline__ void stage_x_zero_f16(unsigned* __restrict__ sm32, int tid) {
    for (int r = 0; r < 4; ++r) {
        int idx4 = tid + 256*r;
        int b = idx4 >> 6, j4 = idx4 & 63;
        int o = b*RSU + 256 + 2*j4;
        sm32[A_HI_OFF + o]     = 0u;
        sm32[A_HI_OFF + o + 1] = 0u;
        sm32[A_LO_OFF + o]     = 0u;
        sm32[A_LO_OFF + o + 1] = 0u;
    }
}

// ---------------- persistent LSTM kernel (split-f16 MFMA, vector-coherent exchange) ----------------
__global__ __launch_bounds__(256, 1)
void lstm_persist(const float* __restrict__ x, const float* __restrict__ target,
                  const float* __restrict__ h0, const float* __restrict__ c0,
                  const float* __restrict__ eWih, const float* __restrict__ eWhh,
                  const float* __restrict__ eb,
                  const float* __restrict__ dWih, const float* __restrict__ dWhh,
                  const float* __restrict__ db,
                  float* __restrict__ hs,
                  unsigned short* __restrict__ hbh,   // [2][64][512] f16-hi
                  unsigned short* __restrict__ hbl,   // [2][64][512] f16-lo
                  unsigned* __restrict__ bar)
{
    extern __shared__ unsigned sm32[];
    float* p_l = (float*)(sm32 + P_OFF);
    float* b_l = (float*)(sm32 + B_OFF);
    float* c_l = (float*)(sm32 + C_OFF);
    unsigned* hst_hi = sm32 + HST_HI;
    unsigned* hst_lo = sm32 + HST_LO;

    const int tid = (int)threadIdx.x;
    const int xcd = (int)(blockIdx.x & 7);
    const int ib  = xcd >> 1;                  // batch group 0..3 (independent)
    const int sub = xcd & 1;
    const int ij  = (int)(blockIdx.x >> 3) | (sub << 5);   // producer id 0..63
    const int b0  = ib * 16;
    const int u0  = ij * 8;
    unsigned* gflags = bar + ib*64;            // 64 monotonic per-producer flags

    load_w_f16(sm32, b_l, eWhh, eWih, eb, u0, tid);
    if (tid < 128) {
        int b = tid >> 3, u = tid & 7;
        c_l[tid] = c0[(size_t)(b0 + b)*HH + u0 + u];
    }
    stage_x_f16(sm32, x + (size_t)b0*DIN, tid);     // x for s=0
    // h_{-1} = h0 (fp32) -> split into A
    for (int r = 0; r < 8; ++r) {
        int idx4 = tid + 256*r;          // 2048 float4 = 16 rows x 128
        int b = idx4 >> 7, j4 = idx4 & 127;
        float4 v = ((const float4*)(h0 + (size_t)(b0 + b)*HH))[j4];
        unsigned h0p, l0p, h1p, l1p;
        pack2(v.x, v.y, h0p, l0p);
        pack2(v.z, v.w, h1p, l1p);
        int o = b*RSU + 2*j4;
        sm32[A_HI_OFF + o]     = h0p;
        sm32[A_HI_OFF + o + 1] = h1p;
        sm32[A_LO_OFF + o]     = l0p;
        sm32[A_LO_OFF + o + 1] = l1p;
    }
    __syncthreads();

    const int lane = tid & 63;
    const int wid  = tid >> 6;
    const int m    = lane & 15;        // A row (batch) / B col (gate-col)
    const int q    = lane >> 4;        // quad
    const int ct   = wid & 1;          // col-tile (16 cols)
    const int kh   = wid >> 1;         // k-half (12 of 24 k-steps)

    const _Float16* aH = (const _Float16*)(sm32 + A_HI_OFF);
    const _Float16* aL = (const _Float16*)(sm32 + A_LO_OFF);
    const _Float16* wH = (const _Float16*)(sm32 + W_HI_OFF);
    const _Float16* wL = (const _Float16*)(sm32 + W_LO_OFF);
    const int aoff = m*RSH + q*8;
    const int woff = (ct*16 + m)*RSH + q*8;

    for (int s = 0; s < 1024; ++s) {
        // ---- 1. split-f16 MFMA GEMM: gates[16b x 32c] over k=768 ----
        f32x4 Chh = {0.f, 0.f, 0.f, 0.f};
        f32x4 Chl = {0.f, 0.f, 0.f, 0.f};
        f32x4 Clh = {0.f, 0.f, 0.f, 0.f};
        {
            const int ks0 = kh * 12;
            #pragma unroll
            for (int i = 0; i < 12; ++i) {
                const int o = (ks0 + i) * 32;
                f16x8 ah = *(const f16x8*)(aH + aoff + o);
                f16x8 al = *(const f16x8*)(aL + aoff + o);
                f16x8 wh = *(const f16x8*)(wH + woff + o);
                f16x8 wl = *(const f16x8*)(wL + woff + o);
                Chh = __builtin_amdgcn_mfma_f32_16x16x32_f16(ah, wh, Chh, 0, 0, 0);
                Chl = __builtin_amdgcn_mfma_f32_16x16x32_f16(ah, wl, Chl, 0, 0, 0);
                Clh = __builtin_amdgcn_mfma_f32_16x16x32_f16(al, wh, Clh, 0, 0, 0);
            }
        }
        {
            float4 C;
            const float sc = 1.0f / 2048.0f;
            C.x = Chh[0] + (Chl[0] + Clh[0]) * sc;
            C.y = Chh[1] + (Chl[1] + Clh[1]) * sc;
            C.z = Chh[2] + (Chl[2] + Clh[2]) * sc;
            C.w = Chh[3] + (Chl[3] + Clh[3]) * sc;
            *(float4*)(p_l + (ct*2 + kh)*320 + m*20 + q*4) = C;
        }
        __syncthreads();

        // ---- 2. elementwise LSTM update -> LDS h-stage (pre-split hi/lo) ----
        float hval = 0.f;
        if (tid < 128) {
            int b = tid >> 3, u = tid & 7;
            float gi = p_l[      u*20 + b] + p_l[320 +      u*20 + b] + b_l[u];
            float gf = p_l[(8+u)*20 + b] + p_l[320 + (8+u)*20 + b] + b_l[8 + u];
            float gg = p_l[640 +   u*20 + b] + p_l[960 +      u*20 + b] + b_l[16 + u];
            float go = p_l[640 + (8+u)*20 + b] + p_l[960 + (8+u)*20 + b] + b_l[24 + u];
            float ii = 1.f / (1.f + expf(-gi));
            float ff = 1.f / (1.f + expf(-gf));
            float g2 = tanhf(gg);
            float oo = 1.f / (1.f + expf(-go));
            float c  = ff * c_l[tid] + ii * g2;
            c_l[tid] = c;
            hval = oo * tanhf(c);
            _Float16 hh = (_Float16)hval;
            _Float16 hl = (_Float16)((hval - (float)hh) * 2048.0f);
            ((unsigned short*)hst_hi)[tid] = f16bits(hh);   // tid = b*8+u
            ((unsigned short*)hst_lo)[tid] = f16bits(hl);
        }
        __syncthreads();

        // ---- 3. publish: wave0 does 32 coalesced coherent 16B stores + flag ----
        if (tid < 64) {
            if (tid < 32) {
                int b    = tid & 15;
                int isLo = tid >> 4;
                u32x4 v = *(const u32x4*)((isLo ? hst_lo : hst_hi) + b*4);
                unsigned short* base = isLo ? hbl : hbh;
                st16_cohere(base + ((size_t)(((s & 1) ^ 1))*BB + b0 + b)*HH + u0, v);
            }
            asm volatile("s_waitcnt vmcnt(0)" ::: "memory");
            if (tid == 0)
                __hip_atomic_store(&gflags[ij], (unsigned)(s + 1),
                                   __ATOMIC_RELAXED, __HIP_MEMORY_SCOPE_AGENT);
        }

        // ---- 4. off-critical-path tail (overlaps other blocks' publishes) ----
        if (s >= 512 && tid < 128) {
            int b = tid >> 3, u = tid & 7;
            hs[((size_t)(s - 512)*BB + (b0 + b))*HH + (u0 + u)] = hval;
        }
        if (s == 511) load_w_f16(sm32, b_l, dWhh, dWih, db, u0, tid);
        {
            int ns = s + 1;
            if (ns < 1024) {
                if (ns == 512)       stage_x_zero_f16(sm32, tid);
                else if (ns < 512)   stage_x_f16(sm32, x + ((size_t)ns*BB + b0)*DIN, tid);
                else                 stage_x_f16(sm32, target + ((size_t)(ns - 513)*BB + b0)*DOUT, tid);
            }
        }

        // ---- 5. wait for all producers of step s; gather h_s for next step ----
        if (s < 1023) {
            if (tid < 64) {
                while (true) {
                    unsigned v = __hip_atomic_load(&gflags[tid], __ATOMIC_RELAXED,
                                                   __HIP_MEMORY_SCOPE_AGENT);
                    if (__ballot(v >= (unsigned)(s + 1)) == ~0ull) break;
                    __builtin_amdgcn_s_sleep(1);
                }
            }
            __syncthreads();
            const unsigned short* srcH = hbh + (size_t)((s + 1) & 1)*BB*HH + (size_t)b0*HH;
            const unsigned short* srcL = hbl + (size_t)((s + 1) & 1)*BB*HH + (size_t)b0*HH;
            u32x4 h0v = ld16_cohere((const u32x4*)srcH + tid);
            u32x4 h1v = ld16_cohere((const u32x4*)srcH + tid + 256);
            u32x4 h2v = ld16_cohere((const u32x4*)srcH + tid + 512);
            u32x4 h3v = ld16_cohere((const u32x4*)srcH + tid + 768);
            u32x4 l0v = ld16_cohere((const u32x4*)srcL + tid);
            u32x4 l1v = ld16_cohere((const u32x4*)srcL + tid + 256);
            u32x4 l2v = ld16_cohere((const u32x4*)srcL + tid + 512);
            u32x4 l3v = ld16_cohere((const u32x4*)srcL + tid + 768);
            asm volatile("s_waitcnt vmcnt(0)"
                         : "+v"(h0v), "+v"(h1v), "+v"(h2v), "+v"(h3v),
                           "+v"(l0v), "+v"(l1v), "+v"(l2v), "+v"(l3v) :: "memory");
            // scatter into padded A rows: uint4 idx -> b = idx>>6, j0 = (idx&63)*4 u32
            {
                int idx, b, j0;
                idx = tid;       b = idx >> 6; j0 = (idx & 63)*4;
                *(u32x4*)(sm32 + A_HI_OFF + b*RSU + j0) = h0v;
                *(u32x4*)(sm32 + A_LO_OFF + b*RSU + j0) = l0v;
                idx = tid + 256; b = idx >> 6; j0 = (idx & 63)*4;
                *(u32x4*)(sm32 + A_HI_OFF + b*RSU + j0) = h1v;
                *(u32x4*)(sm32 + A_LO_OFF + b*RSU + j0) = l1v;
                idx = tid + 512; b = idx >> 6; j0 = (idx & 63)*4;
                *(u32x4*)(sm32 + A_HI_OFF + b*RSU + j0) = h2v;
                *(u32x4*)(sm32 + A_LO_OFF + b*RSU + j0) = l2v;
                idx = tid + 768; b = idx >> 6; j0 = (idx & 63)*4;
                *(u32x4*)(sm32 + A_HI_OFF + b*RSU + j0) = h3v;
                *(u32x4*)(sm32 + A_LO_OFF + b*RSU + j0) = l3v;
            }
        }
        __syncthreads();   // A (h+x), new W all visible before next MFMA
    }
}

// ---------------- FC (logits) kernel ----------------
__global__ __launch_bounds__(256, 1)
void fc_kernel(const float* __restrict__ hs, const float* __restrict__ W,
               const float* __restrict__ bias, float* __restrict__ out)
{
    extern __shared__ float sm[];
    float* hs_l = sm;              // 16 x FCS
    float* w_l  = sm + 16*FCS;     // 32 x FCS

    const int tid = (int)threadIdx.x;
    const int rb = (int)(blockIdx.x >> 3);
    const int cb = (int)(blockIdx.x & 7);

    for (int r = 0; r < 8; ++r) {
        int id = tid + 256*r;
        int b = id >> 7, j = id & 127;
        float4 v = ((const float4*)(hs + (size_t)(rb*16 + b)*HH))[j];
        *(float4*)(hs_l + b*FCS + 4*j) = v;
    }
    for (int r = 0; r < 16; ++r) {
        int id = tid + 256*r;
        int c = id >> 7, j = id & 127;
        float4 v = ((const float4*)(W + (size_t)(cb*32 + c)*HH))[j];
        *(float4*)(w_l + c*FCS + 4*j) = v;
    }
    __syncthreads();

    const int kc = tid & 7, bt = (tid >> 3) & 3, ct = tid >> 5;
    float acc[4][4] = {};
    const float* ap = hs_l + (bt*4)*FCS + 4*kc;
    const float* wp = w_l  + (ct*4)*FCS + 4*kc;
    #pragma unroll 4
    for (int i = 0; i < 16; ++i) {
        float4 av[4], wv[4];
        #pragma unroll
        for (int q = 0; q < 4; ++q) av[q] = *(const float4*)(ap + q*FCS + 32*i);
        #pragma unroll
        for (int q = 0; q < 4; ++q) wv[q] = *(const float4*)(wp + q*FCS + 32*i);
        #pragma unroll
        for (int b2 = 0; b2 < 4; ++b2)
            #pragma unroll
            for (int c2 = 0; c2 < 4; ++c2)
                acc[b2][c2] += av[b2].x*wv[c2].x + av[b2].y*wv[c2].y
                             + av[b2].z*wv[c2].z + av[b2].w*wv[c2].w;
    }
    #pragma unroll
    for (int b2 = 0; b2 < 4; ++b2)
        #pragma unroll
        for (int c2 = 0; c2 < 4; ++c2) {
            float v = acc[b2][c2];
            v += __shfl_xor(v, 1, 64);
            v += __shfl_xor(v, 2, 64);
            v += __shfl_xor(v, 4, 64);
            acc[b2][c2] = v;
        }
    if (kc == 0) {
        #pragma unroll
        for (int b2 = 0; b2 < 4; ++b2)
            #pragma unroll
            for (int c2 = 0; c2 < 4; ++c2) {
                int row = rb*16 + bt*4 + b2;
                int col = cb*32 + ct*4 + c2;
                out[(size_t)row*DOUT + col] = acc[b2][c2] + bias[col];
            }
    }
}

// ---------------- in-place softmax over last dim (256) ----------------
__global__ __launch_bounds__(256, 1)
void softmax_kernel(float* __restrict__ out)
{
    int row  = (int)blockIdx.x * 4 + ((int)threadIdx.x >> 6);
    int lane = (int)threadIdx.x & 63;
    float4 v = ((const float4*)(out + (size_t)row*DOUT))[lane];
    float m = fmaxf(fmaxf(v.x, v.y), fmaxf(v.z, v.w));
    #pragma unroll
    for (int d = 1; d < 64; d <<= 1) m = fmaxf(m, __shfl_xor(m, d, 64));
    float ex = expf(v.x - m), ey = expf(v.y - m), ez = expf(v.z - m), ew = expf(v.w - m);
    float ssum = ex + ey + ez + ew;
    #pragma unroll
    for (int d = 1; d < 64; d <<= 1) ssum += __shfl_xor(ssum, d, 64);
    float inv = 1.f / ssum;
    float4 o = make_float4(ex*inv, ey*inv, ez*inv, ew*inv);
    ((float4*)(out + (size_t)row*DOUT))[lane] = o;
}

// ---------------- flag init (ws is poisoned 0xAA before every call) ----------------
__global__ void init_kernel(unsigned* __restrict__ bar)
{
    bar[threadIdx.x] = 0u;
}

// ---------------- launch ----------------
extern "C" void kernel_launch(void* const* d_in, const int* in_sizes, int n_in,
                              void* d_out, int out_size, void* d_ws, size_t ws_size,
                              hipStream_t stream) {
    (void)in_sizes; (void)n_in; (void)out_size; (void)ws_size;
    const float* x      = (const float*)d_in[0];
    const float* target = (const float*)d_in[1];
    const float* h0     = (const float*)d_in[2];
    const float* c0     = (const float*)d_in[3];
    const float* eWih   = (const float*)d_in[4];
    const float* eWhh   = (const float*)d_in[5];
    const float* eb     = (const float*)d_in[6];
    const float* dWih   = (const float*)d_in[7];
    const float* dWhh   = (const float*)d_in[8];
    const float* db     = (const float*)d_in[9];
    const float* fcW    = (const float*)d_in[10];
    const float* fcb    = (const float*)d_in[11];
    float* out = (float*)d_out;

    unsigned* bar = (unsigned*)d_ws;                        // 1024 u32 flags
    float* hs = (float*)d_ws + 1024;                        // [T*B*H] decoder hidden
    unsigned short* hbh = (unsigned short*)(hs + (size_t)TT*BB*HH);  // [2][64][512] hi
    unsigned short* hbl = hbh + (size_t)2*BB*HH;                     // [2][64][512] lo

    init_kernel<<<dim3(1), dim3(1024), 0, stream>>>(bar);

    lstm_persist<<<dim3(256), dim3(256), SMEM_BYTES, stream>>>(
        x, target, h0, c0, eWih, eWhh, eb, dWih, dWhh, db, hs, hbh, hbl, bar);

    size_t lds_fc = (size_t)(48*FCS) * sizeof(float);       // ~99 KB
    fc_kernel<<<dim3(16384), dim3(256), lds_fc, stream>>>(hs, fcW, fcb, out);

    softmax_kernel<<<dim3(8192), dim3(256), 0, stream>>>(out);
}